// Round 18
// baseline (176.969 us; speedup 1.0000x reference)
//
#include <hip/hip_runtime.h>
#include <hip/hip_bf16.h>
#include <math.h>

// Swin stage: B=31, H=W=64, DIM=60, NH=6, HD=10, WS=8.
// Round 18 = R17 split into attn/MLP kernels per layer (4 main launches).
// Mechanism: per-block latency halves per kernel; residency 5->6 (attn) and
// 6 w/ zero mid-kernel barriers (MLP). y round-trips via global bf16.

#define NB 31
#define NTOK 4096
#define DIM 60
#define NTOT (NB*NTOK)
#define QK_SCALE 0.31622776601683794f
#define LOG2E 1.4426950408889634f
#define QK_SCALE_L2E 0.45622000587446957f

typedef __attribute__((ext_vector_type(8))) short bf16x8;
typedef __attribute__((ext_vector_type(4))) float f32x4;

__device__ __forceinline__ short f2b(float f){
    return __builtin_bit_cast(short, __float2bfloat16(f));
}
__device__ __forceinline__ float b2f(unsigned short u){
    union{unsigned u;float f;}v; v.u=((unsigned)u)<<16; return v.f;
}
__device__ __forceinline__ unsigned pk2(float a,float b){
    return (unsigned)(unsigned short)f2b(a) | ((unsigned)(unsigned short)f2b(b)<<16);
}
#define MFMA16(a,b,c) __builtin_amdgcn_mfma_f32_16x16x32_bf16(a,b,c,0,0,0)
#define EXP2RAW(x) __builtin_amdgcn_exp2f(x)

// packed-weight offsets (shorts, per layer)
#define PK_QKV  0
#define PK_PROJ 13824
#define PK_W1   18432
#define PK_W2   35712
#define PK_STRIDE 52608

// ---------------- pack (unchanged from R17) ----------------
__global__ __launch_bounds__(256) void pack_w(
    const float* __restrict__ qkv_w, const float* __restrict__ proj_w,
    const float* __restrict__ fc1_w, const float* __restrict__ fc2_w,
    const float* __restrict__ rpb, short* __restrict__ pk, float* __restrict__ btab)
{
    const int L = blockIdx.x;
    short* o = pk + (size_t)L * PK_STRIDE;
    const float* qw = qkv_w + L * 10800;
    const float* pw = proj_w + L * 3600;
    const float* w1 = fc1_w + L * 14400;
    const float* w2 = fc2_w + L * 14400;
    const float* rp = rpb + L * 1350;
    const int t0 = blockIdx.y * 256 + threadIdx.x;
    const int STP = 256 * gridDim.y;

    for (int i = t0; i < 192 * 72; i += STP) {
        int row = i / 72, k = i - row * 72;
        int p = row / 96, rg = row - p * 96;
        short v = 0;
        if (rg < 90 && k < 60) {
            int which = rg / 30, idx = rg - which * 30;
            int h = p * 3 + idx / 10, e = idx - (idx / 10) * 10;
            float wv = qw[(which * 60 + h * 10 + e) * 60 + k];
            if (which == 0) wv *= QK_SCALE_L2E;
            v = f2b(wv);
        }
        o[PK_QKV + i] = v;
    }
    for (int i = t0; i < 64 * 72; i += STP) {
        int n = i / 72, k = i - n * 72;
        o[PK_PROJ + i] = (n < 60 && k < 60) ? f2b(pw[n * 60 + k]) : (short)0;
    }
    for (int i = t0; i < 240 * 72; i += STP) {
        int n = i / 72, k = i - n * 72;
        o[PK_W1 + i] = (k < 60) ? f2b(w1[n * 60 + k]) : (short)0;
    }
    for (int i = t0; i < 64 * 264; i += STP) {
        int n = i / 264, k = i - n * 264;
        o[PK_W2 + i] = (n < 60 && k < 240) ? f2b(w2[n * 240 + k]) : (short)0;
    }
    const int NTAB = (L == 0) ? 24576 : 4 * 24576;
    float* bo = btab + (size_t)L * 4 * 24576;
    for (int i = t0; i < NTAB; i += STP) {
        int c = i / 24576, rem = i - c * 24576;
        int h = rem >> 12, rem2 = rem & 4095;
        int ii = rem2 >> 6, j = rem2 & 63;
        int iy = ii >> 3, ix = ii & 7, jy = j >> 3, jx = j & 7;
        float v = rp[((iy - jy + 7) * 15 + (ix - jx + 7)) * 6 + h];
        int riy = (c & 2) ? (iy < 4 ? 1 : 2) : 0;
        int rix = (c & 1) ? (ix < 4 ? 1 : 2) : 0;
        int rjy = (c & 2) ? (jy < 4 ? 1 : 2) : 0;
        int rjx = (c & 1) ? (jx < 4 ? 1 : 2) : 0;
        if (riy != rjy || rix != rjx) v -= 100.f;
        bo[i] = v * LOG2E;
    }
}

// ---------------- attention kernel: LN1 + attn + proj + residual -> y (bf16 rows) ----
// L=0: in fp32 (60,NTOT) d-major, shift 0.  L=1: in bf16 (NTOT,60), shift 4.
// LDS: R1[64*72]=9216B; R2[8816]=qk[64][104](6656)+vT[3][10][72]@6656(2160)
//  =17632B; y staging aliases R2 stride 136 (max 8631 < 8816). Total 26848B -> 6/CU.
template<int L>
__global__ __launch_bounds__(256, 5) void swin_attn(
    const void* __restrict__ xin_v, unsigned short* __restrict__ yout,
    const float* __restrict__ g1, const float* __restrict__ b1,
    const short* __restrict__ pk, const float* __restrict__ btab,
    const float* __restrict__ qkv_b, const float* __restrict__ proj_b)
{
    __shared__ __attribute__((aligned(16))) short R1[64 * 72];
    __shared__ __attribute__((aligned(16))) short R2[8816];

    const f32x4 Z4 = {0.f, 0.f, 0.f, 0.f};
    const bf16x8 Z8 = {0, 0, 0, 0, 0, 0, 0, 0};

    const int tid = threadIdx.x;
    const int blk = ((blockIdx.x & 7) * 248) + (blockIdx.x >> 3);
    const int b = blk >> 6, w = blk & 63, wy = w >> 3, wx = w & 7;
    const int shift = L ? 4 : 0;
    const int cls = L ? (((wy == 7) ? 2 : 0) + ((wx == 7) ? 1 : 0)) : 0;

    const float* xf = (const float*)xin_v;
    const unsigned short* xb = (const unsigned short*)xin_v;

    // zero Q/K e-pads
    for (int i = tid; i < 64 * 18; i += 256) {
        int row = i / 18, t = i - row * 18, bc = t / 3, k = t - bc * 3;
        *(int*)&R2[row * 104 + bc * 16 + 10 + 2 * k] = 0;
    }

    // LN1 -> R1; residual x packed in regs
    const int tk = tid >> 2, l4 = tid & 3;
    const int tok = (((wy * 8 + (tk >> 3) + shift) & 63) << 6)
                  + ((wx * 8 + (tk & 7) + shift) & 63);
    unsigned xpk[8];
    if (L == 0) {
        float xr[15]; float s = 0.f, s2 = 0.f;
#pragma unroll
        for (int dd = 0; dd < 15; ++dd) {
            float v = xf[(size_t)(l4 * 15 + dd) * NTOT + b * NTOK + tok];
            xr[dd] = v; s += v; s2 += v * v;
        }
        s  += __shfl_xor(s, 1);  s  += __shfl_xor(s, 2);
        s2 += __shfl_xor(s2, 1); s2 += __shfl_xor(s2, 2);
        const float mu = s * (1.f / 60.f);
        const float rs = rsqrtf(s2 * (1.f / 60.f) - mu * mu + 1e-5f);
#pragma unroll
        for (int dd = 0; dd < 15; ++dd) {
            int d = l4 * 15 + dd;
            R1[tk * 72 + d] = f2b((xr[dd] - mu) * rs * g1[d] + b1[d]);
        }
#pragma unroll
        for (int u = 0; u < 3; ++u) R1[tk * 72 + 60 + l4 * 3 + u] = 0;
#pragma unroll
        for (int u = 0; u < 7; ++u) xpk[u] = pk2(xr[2 * u], xr[2 * u + 1]);
        xpk[7] = pk2(xr[14], 0.f);
    } else {
        float xr[16]; float s = 0.f, s2 = 0.f;
        const int nd = (l4 == 3) ? 6 : 8, c0 = l4 * 16;
        const unsigned* rp_ = (const unsigned*)(xb + ((size_t)b * NTOK + tok) * DIM) + l4 * 8;
#pragma unroll
        for (int j = 0; j < 8; ++j) {
            if (j < nd) {
                unsigned u = rp_[j];
                xpk[j] = u;
                float v0 = b2f((unsigned short)(u & 0xffff));
                float v1 = b2f((unsigned short)(u >> 16));
                xr[2 * j] = v0; xr[2 * j + 1] = v1;
                s += v0 + v1; s2 += v0 * v0 + v1 * v1;
            }
        }
        s  += __shfl_xor(s, 1);  s  += __shfl_xor(s, 2);
        s2 += __shfl_xor(s2, 1); s2 += __shfl_xor(s2, 2);
        const float mu = s * (1.f / 60.f);
        const float rs = rsqrtf(s2 * (1.f / 60.f) - mu * mu + 1e-5f);
#pragma unroll
        for (int j = 0; j < 8; ++j) {
            if (j < nd) {
                int d = c0 + 2 * j;
                float n0 = (xr[2 * j] - mu) * rs * g1[d] + b1[d];
                float n1 = (xr[2 * j + 1] - mu) * rs * g1[d + 1] + b1[d + 1];
                *(unsigned*)&R1[tk * 72 + d] = pk2(n0, n1);
            }
        }
        if (l4 == 3) {
#pragma unroll
            for (int u = 0; u < 3; ++u) *(unsigned*)&R1[tk * 72 + 60 + 2 * u] = 0;
        }
    }

    const int lane = tid & 63, r16 = lane & 15, g = lane >> 4;
    const int m0 = (tid >> 6) << 4;

    bf16x8 a0 = *(const bf16x8*)&R1[(m0 + r16) * 72 + g * 8];
    bf16x8 a1 = *(const bf16x8*)&R1[(m0 + r16) * 72 + 32 + g * 8];
    const float* btc = btab + (size_t)cls * 24576 + (m0 + r16) * 64;

    for (int p = 0; p < 2; ++p) {
#pragma unroll
        for (int nt = 0; nt < 6; ++nt) {
            const short* wr = pk + PK_QKV + (size_t)(p * 96 + nt * 16 + r16) * 72;
            bf16x8 w0 = *(const bf16x8*)(wr + g * 8);
            bf16x8 w1v = *(const bf16x8*)(wr + 32 + g * 8);
            int c = nt * 16 + r16;
            int which = 0, hl = 0, e = 0; float bias = 0.f;
            if (c < 90) {
                which = c / 30; int idx = c - which * 30;
                hl = idx / 10; e = idx - hl * 10;
                bias = qkv_b[which * 60 + (p * 3 + hl) * 10 + e];
                if (which == 0) bias *= QK_SCALE_L2E;
            }
            f32x4 acc = {bias, bias, bias, bias};
            acc = MFMA16(a0, w0, acc);
            acc = MFMA16(a1, w1v, acc);
            if (c < 90) {
                if (which == 0) {
#pragma unroll
                    for (int r = 0; r < 4; ++r)
                        R2[(m0 + g * 4 + r) * 104 + hl * 16 + e] = f2b(acc[r]);
                } else if (which == 1) {
#pragma unroll
                    for (int r = 0; r < 4; ++r)
                        R2[(m0 + g * 4 + r) * 104 + 48 + hl * 16 + e] = f2b(acc[r]);
                } else {
#pragma unroll
                    for (int r = 0; r < 2; ++r)
                        *(unsigned*)&R2[6656 + (hl * 10 + e) * 72 + m0 + g * 4 + 2 * r] =
                            pk2(acc[2 * r], acc[2 * r + 1]);
                }
            }
        }
        __syncthreads();

#pragma unroll
        for (int hl = 0; hl < 3; ++hl) {
            const int h = p * 3 + hl;
            bf16x8 qa = Z8;
            if (g < 2) qa = *(const bf16x8*)&R2[(m0 + r16) * 104 + hl * 16 + g * 8];
            const float* bh = btc + h * 4096;
            f32x4 sv[4];
#pragma unroll
            for (int nt = 0; nt < 4; ++nt) {
                bf16x8 kb = Z8;
                if (g < 2) kb = *(const bf16x8*)&R2[(nt * 16 + r16) * 104 + 48 + hl * 16 + g * 8];
                sv[nt] = MFMA16(kb, qa, *(const f32x4*)&bh[nt * 16 + g * 4]);
            }
            float sum = 0.f;
#pragma unroll
            for (int nt = 0; nt < 4; ++nt)
#pragma unroll
                for (int r = 0; r < 4; ++r) {
                    float e = EXP2RAW(sv[nt][r]);
                    sv[nt][r] = e; sum += e;
                }
            sum += __shfl_xor(sum, 16);
            sum += __shfl_xor(sum, 32);
            const float inv = 1.f / sum;

            unsigned qd00 = pk2(sv[0][0], sv[0][1]), qd01 = pk2(sv[0][2], sv[0][3]);
            unsigned qd10 = pk2(sv[1][0], sv[1][1]), qd11 = pk2(sv[1][2], sv[1][3]);
            unsigned qd20 = pk2(sv[2][0], sv[2][1]), qd21 = pk2(sv[2][2], sv[2][3]);
            unsigned qd30 = pk2(sv[3][0], sv[3][1]), qd31 = pk2(sv[3][2], sv[3][3]);
            const int sA = (r16 + ((g & 1) << 5)) << 2;
            const int sB = sA + 64;
            const bool hi = (g >> 1) & 1;
            union { unsigned u[4]; bf16x8 v; } pb0, pb1;
            {
                unsigned x0 = __builtin_amdgcn_ds_bpermute(sA, (int)qd00);
                unsigned y0 = __builtin_amdgcn_ds_bpermute(sA, (int)qd10);
                pb0.u[0] = hi ? y0 : x0;
                unsigned x1 = __builtin_amdgcn_ds_bpermute(sA, (int)qd01);
                unsigned y1 = __builtin_amdgcn_ds_bpermute(sA, (int)qd11);
                pb0.u[1] = hi ? y1 : x1;
                unsigned x2 = __builtin_amdgcn_ds_bpermute(sB, (int)qd00);
                unsigned y2 = __builtin_amdgcn_ds_bpermute(sB, (int)qd10);
                pb0.u[2] = hi ? y2 : x2;
                unsigned x3 = __builtin_amdgcn_ds_bpermute(sB, (int)qd01);
                unsigned y3 = __builtin_amdgcn_ds_bpermute(sB, (int)qd11);
                pb0.u[3] = hi ? y3 : x3;
                unsigned u0 = __builtin_amdgcn_ds_bpermute(sA, (int)qd20);
                unsigned v0 = __builtin_amdgcn_ds_bpermute(sA, (int)qd30);
                pb1.u[0] = hi ? v0 : u0;
                unsigned u1 = __builtin_amdgcn_ds_bpermute(sA, (int)qd21);
                unsigned v1 = __builtin_amdgcn_ds_bpermute(sA, (int)qd31);
                pb1.u[1] = hi ? v1 : u1;
                unsigned u2 = __builtin_amdgcn_ds_bpermute(sB, (int)qd20);
                unsigned v2 = __builtin_amdgcn_ds_bpermute(sB, (int)qd30);
                pb1.u[2] = hi ? v2 : u2;
                unsigned u3 = __builtin_amdgcn_ds_bpermute(sB, (int)qd21);
                unsigned v3 = __builtin_amdgcn_ds_bpermute(sB, (int)qd31);
                pb1.u[3] = hi ? v3 : u3;
            }
            bf16x8 va0 = Z8, va1 = Z8;
            if (r16 < 10) {
                va0 = *(const bf16x8*)&R2[6656 + (hl * 10 + r16) * 72 + g * 8];
                va1 = *(const bf16x8*)&R2[6656 + (hl * 10 + r16) * 72 + 32 + g * 8];
            }
            f32x4 o = MFMA16(va0, pb0.v, Z4);
            o = MFMA16(va1, pb1.v, o);
            if (g < 2) {
                *(unsigned*)&R1[(m0 + r16) * 72 + h * 10 + g * 4]     = pk2(o[0] * inv, o[1] * inv);
                *(unsigned*)&R1[(m0 + r16) * 72 + h * 10 + g * 4 + 2] = pk2(o[2] * inv, o[3] * inv);
            } else if (g == 2) {
                *(unsigned*)&R1[(m0 + r16) * 72 + h * 10 + 8] = pk2(o[0] * inv, o[1] * inv);
            }
        }
        __syncthreads();
    }

    // proj (+bias) -> R1 rows
    {
        bf16x8 oa0 = *(const bf16x8*)&R1[(m0 + r16) * 72 + g * 8];
        bf16x8 oa1 = *(const bf16x8*)&R1[(m0 + r16) * 72 + 32 + g * 8];
#pragma unroll
        for (int nt = 0; nt < 4; ++nt) {
            const short* wr = pk + PK_PROJ + (size_t)(nt * 16 + r16) * 72;
            bf16x8 w0 = *(const bf16x8*)(wr + g * 8);
            bf16x8 w1v = *(const bf16x8*)(wr + 32 + g * 8);
            int d = nt * 16 + r16;
            float pb_ = (d < 60) ? proj_b[d] : 0.f;
            f32x4 acc = {pb_, pb_, pb_, pb_};
            acc = MFMA16(oa0, w0, acc);
            acc = MFMA16(oa1, w1v, acc);
            if (d < 60) {
#pragma unroll
                for (int r = 0; r < 4; ++r)
                    R1[(m0 + g * 4 + r) * 72 + d] = f2b(acc[r]);
            }
        }
    }

    // residual (xpk) + stage y bf16 into R2 stride 136 (wave-local rows)
    if (L == 0) {
#pragma unroll
        for (int dd = 0; dd < 15; ++dd) {
            int d = l4 * 15 + dd;
            float xv = b2f((unsigned short)((dd & 1) ? (xpk[dd >> 1] >> 16)
                                                    : (xpk[dd >> 1] & 0xffff)));
            R2[tk * 136 + d] = f2b(xv + b2f((unsigned short)R1[tk * 72 + d]));
        }
    } else {
        const int nd = (l4 == 3) ? 6 : 8, c0 = l4 * 16;
#pragma unroll
        for (int j = 0; j < 8; ++j) {
            if (j < nd) {
                int d = c0 + 2 * j;
                float y0 = b2f((unsigned short)(xpk[j] & 0xffff))
                         + b2f((unsigned short)R1[tk * 72 + d]);
                float y1 = b2f((unsigned short)(xpk[j] >> 16))
                         + b2f((unsigned short)R1[tk * 72 + d + 1]);
                *(unsigned*)&R2[tk * 136 + d] = pk2(y0, y1);
            }
        }
    }
    __syncthreads();

    // coalesced y store (bf16 rows, un-shifted global token order)
    {
        unsigned* ob = (unsigned*)yout;
        const size_t gbase = (size_t)b * NTOK * 30;
        for (int i = tid; i < 1920; i += 256) {
            int r = i / 30, c = i - r * 30;
            int gt = (((wy * 8 + (r >> 3) + shift) & 63) << 6)
                   + ((wx * 8 + (r & 7) + shift) & 63);
            ob[gbase + (size_t)gt * 30 + c] = *(unsigned*)&R2[r * 136 + 2 * c];
        }
    }
}

// ---------------- MLP kernel: LN2 + fc1 + GELU + fc2 + residual ----------------
// Token-blocks (64 tokens/block, no windows). In: y bf16 rows.
// OUTF=0: out bf16 rows. OUTF=1: out fp32 (60,NTOT) d-major.
// LDS: Ry[64*72]=9216B + R2[8704]=17408B (ln2/hb/staging). 26624B -> 6/CU.
// No barrier until the final store (all phases wave-local).
template<int OUTF>
__global__ __launch_bounds__(256, 5) void swin_mlp(
    const unsigned short* __restrict__ yin, void* __restrict__ xout_v,
    const float* __restrict__ g2, const float* __restrict__ b2,
    const short* __restrict__ pk,
    const float* __restrict__ fc1_b, const float* __restrict__ fc2_b)
{
    __shared__ __attribute__((aligned(16))) short Ry[64 * 72];
    __shared__ __attribute__((aligned(16))) short R2[8704];

    const int tid = threadIdx.x;
    const size_t t0 = (size_t)blockIdx.x * 64;
    const int tk = tid >> 2, l4 = tid & 3;

    // load y row + LN2 -> R2 stride 136; y -> Ry rows
    {
        float yr[16]; float s = 0.f, s2 = 0.f;
        const int nd = (l4 == 3) ? 6 : 8, c0 = l4 * 16;
        unsigned ypk[8];
        const unsigned* rp_ = (const unsigned*)(yin + (t0 + tk) * DIM) + l4 * 8;
#pragma unroll
        for (int j = 0; j < 8; ++j) {
            if (j < nd) {
                unsigned u = rp_[j];
                ypk[j] = u;
                float v0 = b2f((unsigned short)(u & 0xffff));
                float v1 = b2f((unsigned short)(u >> 16));
                yr[2 * j] = v0; yr[2 * j + 1] = v1;
                s += v0 + v1; s2 += v0 * v0 + v1 * v1;
            }
        }
        s  += __shfl_xor(s, 1);  s  += __shfl_xor(s, 2);
        s2 += __shfl_xor(s2, 1); s2 += __shfl_xor(s2, 2);
        const float mu = s * (1.f / 60.f);
        const float rs = rsqrtf(s2 * (1.f / 60.f) - mu * mu + 1e-5f);
#pragma unroll
        for (int j = 0; j < 8; ++j) {
            if (j < nd) {
                int d = c0 + 2 * j;
                *(unsigned*)&Ry[tk * 72 + d] = ypk[j];
                float n0 = (yr[2 * j] - mu) * rs * g2[d] + b2[d];
                float n1 = (yr[2 * j + 1] - mu) * rs * g2[d + 1] + b2[d + 1];
                *(unsigned*)&R2[tk * 136 + d] = pk2(n0, n1);
            }
        }
        if (l4 == 3) {
#pragma unroll
            for (int u = 0; u < 3; ++u) *(unsigned*)&R2[tk * 136 + 60 + 2 * u] = 0;
        }
    }

    const int lane = tid & 63, r16 = lane & 15, g = lane >> 4;
    const int m0 = (tid >> 6) << 4;

    bf16x8 la0 = *(const bf16x8*)&R2[(m0 + r16) * 136 + g * 8];
    bf16x8 la1 = *(const bf16x8*)&R2[(m0 + r16) * 136 + 32 + g * 8];

    f32x4 acc2[4];
#pragma unroll
    for (int nt = 0; nt < 4; ++nt) {
        int d = nt * 16 + r16;
        float fb = (d < 60) ? fc2_b[d] : 0.f;
        acc2[nt] = (f32x4){fb, fb, fb, fb};
    }

    const f32x4 Z4 = {0.f, 0.f, 0.f, 0.f};
    (void)Z4;

    // GEMM1 half A (c 0..127) -> hb
#pragma unroll
    for (int nt = 0; nt < 8; ++nt) {
        const short* wr = pk + PK_W1 + (size_t)(nt * 16 + r16) * 72;
        bf16x8 w0 = *(const bf16x8*)(wr + g * 8);
        bf16x8 w1v = *(const bf16x8*)(wr + 32 + g * 8);
        int c = nt * 16 + r16;
        float fb = fc1_b[c];
        f32x4 acc = {fb, fb, fb, fb};
        acc = MFMA16(la0, w0, acc);
        acc = MFMA16(la1, w1v, acc);
#pragma unroll
        for (int r = 0; r < 4; ++r) {
            float u = acc[r];
            float zz = 2.302208235f * u + 0.10294353f * (u * u * u);
            float ge = u * __builtin_amdgcn_rcpf(1.f + EXP2RAW(-zz));
            R2[(m0 + g * 4 + r) * 136 + c] = f2b(ge);
        }
    }
    // GEMM2 pass 1 (K 0..127)
#pragma unroll
    for (int kk = 0; kk < 4; ++kk) {
        bf16x8 ha = *(const bf16x8*)&R2[(m0 + r16) * 136 + kk * 32 + g * 8];
#pragma unroll
        for (int nt = 0; nt < 4; ++nt) {
            const short* wr = pk + PK_W2 + (size_t)(nt * 16 + r16) * 264 + kk * 32 + g * 8;
            acc2[nt] = MFMA16(ha, *(const bf16x8*)wr, acc2[nt]);
        }
    }
    // zero hb cols 112..127 (own rows)
    *(int*)&R2[(m0 + r16) * 136 + 112 + g * 4]     = 0;
    *(int*)&R2[(m0 + r16) * 136 + 112 + g * 4 + 2] = 0;
    // GEMM1 half B (c 128..239) -> hb cols 0..111
#pragma unroll
    for (int nt = 0; nt < 7; ++nt) {
        const short* wr = pk + PK_W1 + (size_t)(128 + nt * 16 + r16) * 72;
        bf16x8 w0 = *(const bf16x8*)(wr + g * 8);
        bf16x8 w1v = *(const bf16x8*)(wr + 32 + g * 8);
        int c = nt * 16 + r16;
        float fb = fc1_b[128 + c];
        f32x4 acc = {fb, fb, fb, fb};
        acc = MFMA16(la0, w0, acc);
        acc = MFMA16(la1, w1v, acc);
#pragma unroll
        for (int r = 0; r < 4; ++r) {
            float u = acc[r];
            float zz = 2.302208235f * u + 0.10294353f * (u * u * u);
            float ge = u * __builtin_amdgcn_rcpf(1.f + EXP2RAW(-zz));
            R2[(m0 + g * 4 + r) * 136 + c] = f2b(ge);
        }
    }
    // GEMM2 pass 2 (K 128..255)
#pragma unroll
    for (int kk = 0; kk < 4; ++kk) {
        bf16x8 ha = *(const bf16x8*)&R2[(m0 + r16) * 136 + kk * 32 + g * 8];
#pragma unroll
        for (int nt = 0; nt < 4; ++nt) {
            const short* wr = pk + PK_W2 + (size_t)(nt * 16 + r16) * 264 + 128 + kk * 32 + g * 8;
            acc2[nt] = MFMA16(ha, *(const bf16x8*)wr, acc2[nt]);
        }
    }

    // epilogue: v = y + mlp; stage (wave-local), then coalesced store
#pragma unroll
    for (int nt = 0; nt < 4; ++nt) {
        int d = nt * 16 + r16;
        if (d < 60) {
#pragma unroll
            for (int r = 0; r < 4; ++r) {
                float yv = b2f((unsigned short)Ry[(m0 + g * 4 + r) * 72 + d]);
                float v = yv + acc2[nt][r];
                if (OUTF == 0) R2[(m0 + g * 4 + r) * 136 + d] = f2b(v);
                else           ((float*)R2)[(m0 + g * 4 + r) * 68 + d] = v;
            }
        }
    }
    __syncthreads();

    if (OUTF == 0) {
        unsigned* ob = (unsigned*)xout_v;
        const size_t gbase = t0 * 30;
        for (int i = tid; i < 1920; i += 256) {
            int r = i / 30, c = i - r * 30;
            ob[gbase + (size_t)r * 30 + c] = *(unsigned*)&R2[r * 136 + 2 * c];
        }
    } else {
        float* of = (float*)xout_v;
        for (int i = tid; i < 3840; i += 256) {
            int d = i >> 6, tt = i & 63;
            of[(size_t)d * NTOT + t0 + tt] = ((const float*)R2)[tt * 68 + d];
        }
    }
}

extern "C" void kernel_launch(void* const* d_in, const int* in_sizes, int n_in,
                              void* d_out, int out_size, void* d_ws, size_t ws_size,
                              hipStream_t stream)
{
    const float* x       = (const float*)d_in[0];
    const float* norm1_g = (const float*)d_in[1];
    const float* norm1_b = (const float*)d_in[2];
    const float* qkv_w   = (const float*)d_in[3];
    const float* qkv_b   = (const float*)d_in[4];
    const float* rpb     = (const float*)d_in[5];
    const float* proj_w  = (const float*)d_in[6];
    const float* proj_b  = (const float*)d_in[7];
    const float* norm2_g = (const float*)d_in[8];
    const float* norm2_b = (const float*)d_in[9];
    const float* fc1_w   = (const float*)d_in[10];
    const float* fc1_b   = (const float*)d_in[11];
    const float* fc2_w   = (const float*)d_in[12];
    const float* fc2_b   = (const float*)d_in[13];

    unsigned short* bufA = (unsigned short*)d_ws;                       // y buffer
    short* pk  = (short*)((char*)d_ws + (size_t)NTOT * DIM * 2);
    float* btab = (float*)((char*)pk + 2 * PK_STRIDE * 2);
    unsigned short* xB = (unsigned short*)d_out;                        // mid activations (d_out lower half)

    dim3 block(256);
    pack_w<<<dim3(2, 64), block, 0, stream>>>(qkv_w, proj_w, fc1_w, fc2_w, rpb, pk, btab);

    dim3 grid(NB * 64);
    // layer 0
    swin_attn<0><<<grid, block, 0, stream>>>(
        (const void*)x, bufA, norm1_g, norm1_b, pk, btab, qkv_b, proj_b);
    swin_mlp<0><<<grid, block, 0, stream>>>(
        bufA, (void*)xB, norm2_g, norm2_b, pk, fc1_b, fc2_b);
    // layer 1
    swin_attn<1><<<grid, block, 0, stream>>>(
        (const void*)xB, bufA, norm1_g + 60, norm1_b + 60,
        pk + PK_STRIDE, btab + 4 * 24576, qkv_b + 180, proj_b + 60);
    swin_mlp<1><<<grid, block, 0, stream>>>(
        bufA, d_out, norm2_g + 60, norm2_b + 60,
        pk + PK_STRIDE, fc1_b + 240, fc2_b + 60);

    (void)in_sizes; (void)n_in; (void)out_size; (void)ws_size;
}

// Round 19
// 162.869 us; speedup vs baseline: 1.0866x; 1.0866x over previous
//
#include <hip/hip_runtime.h>
#include <hip/hip_bf16.h>
#include <math.h>

// Swin stage: B=31, H=W=64, DIM=60, NH=6, HD=10, WS=8. One fused kernel/layer.
// Round 19 = REVERT to Round-17 (best: 163.15us). R18's attn/MLP split
// regressed (176.97): residency was never the binding constraint (R13),
// so halving kernels only added a y round-trip + launch tails.
// R17 = compacted-LDS fused layer + exp2-folded softmax/GELU (raw v_exp_f32)
// + head-unroll ILP + wide pack_w.

#define NB 31
#define NTOK 4096
#define DIM 60
#define NTOT (NB*NTOK)
#define QK_SCALE 0.31622776601683794f
#define LOG2E 1.4426950408889634f
#define QK_SCALE_L2E 0.45622000587446957f   // QK_SCALE * LOG2E

typedef __attribute__((ext_vector_type(8))) short bf16x8;
typedef __attribute__((ext_vector_type(4))) float f32x4;

__device__ __forceinline__ short f2b(float f){
    return __builtin_bit_cast(short, __float2bfloat16(f));
}
__device__ __forceinline__ float b2f(unsigned short u){
    union{unsigned u;float f;}v; v.u=((unsigned)u)<<16; return v.f;
}
__device__ __forceinline__ unsigned pk2(float a,float b){
    return (unsigned)(unsigned short)f2b(a) | ((unsigned)(unsigned short)f2b(b)<<16);
}
#define MFMA16(a,b,c) __builtin_amdgcn_mfma_f32_16x16x32_bf16(a,b,c,0,0,0)
#define EXP2RAW(x) __builtin_amdgcn_exp2f(x)   // bare v_exp_f32, no denorm fixup

// packed-weight offsets (shorts, per layer)
#define PK_QKV  0        // [192][72] head-grouped, q rows pre-scaled by QK_SCALE*log2e
#define PK_PROJ 13824    // [64][72]
#define PK_W1   18432    // [240][72]
#define PK_W2   35712    // [64][264]
#define PK_STRIDE 52608

// ---------------- pack: weights -> bf16, bias+mask (x log2e) -> fp32 table ----------------
__global__ __launch_bounds__(256) void pack_w(
    const float* __restrict__ qkv_w, const float* __restrict__ proj_w,
    const float* __restrict__ fc1_w, const float* __restrict__ fc2_w,
    const float* __restrict__ rpb, short* __restrict__ pk, float* __restrict__ btab)
{
    const int L = blockIdx.x;
    short* o = pk + (size_t)L * PK_STRIDE;
    const float* qw = qkv_w + L * 10800;
    const float* pw = proj_w + L * 3600;
    const float* w1 = fc1_w + L * 14400;
    const float* w2 = fc2_w + L * 14400;
    const float* rp = rpb + L * 1350;
    const int t0 = blockIdx.y * 256 + threadIdx.x;
    const int STP = 256 * gridDim.y;

    // qkv rows: triple-group p: [q h(3p..3p+2) 30][k 30][v 30][pad 6]
    for (int i = t0; i < 192 * 72; i += STP) {
        int row = i / 72, k = i - row * 72;
        int p = row / 96, rg = row - p * 96;
        short v = 0;
        if (rg < 90 && k < 60) {
            int which = rg / 30, idx = rg - which * 30;
            int h = p * 3 + idx / 10, e = idx - (idx / 10) * 10;
            float wv = qw[(which * 60 + h * 10 + e) * 60 + k];
            if (which == 0) wv *= QK_SCALE_L2E;
            v = f2b(wv);
        }
        o[PK_QKV + i] = v;
    }
    for (int i = t0; i < 64 * 72; i += STP) {
        int n = i / 72, k = i - n * 72;
        o[PK_PROJ + i] = (n < 60 && k < 60) ? f2b(pw[n * 60 + k]) : (short)0;
    }
    for (int i = t0; i < 240 * 72; i += STP) {
        int n = i / 72, k = i - n * 72;
        o[PK_W1 + i] = (k < 60) ? f2b(w1[n * 60 + k]) : (short)0;
    }
    for (int i = t0; i < 64 * 264; i += STP) {
        int n = i / 264, k = i - n * 264;
        o[PK_W2 + i] = (n < 60 && k < 240) ? f2b(w2[n * 240 + k]) : (short)0;
    }
    // fp32 bias+mask table [L][cls][h][i][j], pre-scaled by log2e.
    // Layer 0 (shift=0) only reads cls 0 -> skip cls 1..3.
    const int NTAB = (L == 0) ? 24576 : 4 * 24576;
    float* bo = btab + (size_t)L * 4 * 24576;
    for (int i = t0; i < NTAB; i += STP) {
        int c = i / 24576, rem = i - c * 24576;
        int h = rem >> 12, rem2 = rem & 4095;
        int ii = rem2 >> 6, j = rem2 & 63;
        int iy = ii >> 3, ix = ii & 7, jy = j >> 3, jx = j & 7;
        float v = rp[((iy - jy + 7) * 15 + (ix - jx + 7)) * 6 + h];
        int riy = (c & 2) ? (iy < 4 ? 1 : 2) : 0;
        int rix = (c & 1) ? (ix < 4 ? 1 : 2) : 0;
        int rjy = (c & 2) ? (jy < 4 ? 1 : 2) : 0;
        int rjx = (c & 1) ? (jx < 4 ? 1 : 2) : 0;
        if (riy != rjy || rix != rjx) v -= 100.f;
        bo[i] = v * LOG2E;
    }
}

// ---------------- fused layer ----------------
// L=0: in fp32 (60,NTOT) d-major, shift 0, out bf16 (NTOT,60)
// L=1: in bf16 (NTOT,60), shift 4, out fp32 (60,NTOT)
// LDS: R1[64][72]; R2[8832] = qk[64][104] + vT[3][10][72] @6656 (max 8807),
// aliased with ln2/hb[64][136] (max 8695) and fp32 staging (max 8686).
template<int L>
__global__ __launch_bounds__(256, 5) void swin_layer(
    const void* __restrict__ xin_v, void* __restrict__ xout_v,
    const float* __restrict__ g1, const float* __restrict__ b1,
    const float* __restrict__ g2, const float* __restrict__ b2,
    const short* __restrict__ pk, const float* __restrict__ btab,
    const float* __restrict__ qkv_b, const float* __restrict__ proj_b,
    const float* __restrict__ fc1_b, const float* __restrict__ fc2_b)
{
    __shared__ __attribute__((aligned(16))) short R1[64 * 72];  //  9216 B
    __shared__ __attribute__((aligned(16))) short R2[8832];     // 17664 B

    const f32x4 Z4 = {0.f, 0.f, 0.f, 0.f};
    const bf16x8 Z8 = {0, 0, 0, 0, 0, 0, 0, 0};

    const int tid = threadIdx.x;
    // chunked XCD swizzle: consecutive logical windows share an XCD's L2
    const int blk = ((blockIdx.x & 7) * 248) + (blockIdx.x >> 3);
    const int b = blk >> 6, w = blk & 63, wy = w >> 3, wx = w & 7;
    const int shift = L ? 4 : 0;
    const int cls = L ? (((wy == 7) ? 2 : 0) + ((wx == 7) ? 1 : 0)) : 0;

    const float* xf = (const float*)xin_v;
    const unsigned short* xb = (const unsigned short*)xin_v;

    // ---- A: zero Q/K e-pads (cols 10..15 of each 16-block) ----
    for (int i = tid; i < 64 * 18; i += 256) {
        int row = i / 18, t = i - row * 18, bc = t / 3, k = t - bc * 3;
        *(int*)&R2[row * 104 + bc * 16 + 10 + 2 * k] = 0;
    }

    // ---- LN1 -> R1; keep packed residual x in regs (xpk) ----
    const int tk = tid >> 2, l4 = tid & 3;
    const int tok = (((wy * 8 + (tk >> 3) + shift) & 63) << 6)
                  + ((wx * 8 + (tk & 7) + shift) & 63);
    unsigned xpk[8];
    if (L == 0) {
        float xr[15]; float s = 0.f, s2 = 0.f;
#pragma unroll
        for (int dd = 0; dd < 15; ++dd) {
            float v = xf[(size_t)(l4 * 15 + dd) * NTOT + b * NTOK + tok];
            xr[dd] = v; s += v; s2 += v * v;
        }
        s  += __shfl_xor(s, 1);  s  += __shfl_xor(s, 2);
        s2 += __shfl_xor(s2, 1); s2 += __shfl_xor(s2, 2);
        const float mu = s * (1.f / 60.f);
        const float rs = rsqrtf(s2 * (1.f / 60.f) - mu * mu + 1e-5f);
#pragma unroll
        for (int dd = 0; dd < 15; ++dd) {
            int d = l4 * 15 + dd;
            R1[tk * 72 + d] = f2b((xr[dd] - mu) * rs * g1[d] + b1[d]);
        }
#pragma unroll
        for (int u = 0; u < 3; ++u) R1[tk * 72 + 60 + l4 * 3 + u] = 0;
#pragma unroll
        for (int u = 0; u < 7; ++u) xpk[u] = pk2(xr[2 * u], xr[2 * u + 1]);
        xpk[7] = pk2(xr[14], 0.f);
    } else {
        float xr[16]; float s = 0.f, s2 = 0.f;
        const int nd = (l4 == 3) ? 6 : 8, c0 = l4 * 16;
        const unsigned* rp_ = (const unsigned*)(xb + ((size_t)b * NTOK + tok) * DIM) + l4 * 8;
#pragma unroll
        for (int j = 0; j < 8; ++j) {
            if (j < nd) {
                unsigned u = rp_[j];
                xpk[j] = u;
                float v0 = b2f((unsigned short)(u & 0xffff));
                float v1 = b2f((unsigned short)(u >> 16));
                xr[2 * j] = v0; xr[2 * j + 1] = v1;
                s += v0 + v1; s2 += v0 * v0 + v1 * v1;
            }
        }
        s  += __shfl_xor(s, 1);  s  += __shfl_xor(s, 2);
        s2 += __shfl_xor(s2, 1); s2 += __shfl_xor(s2, 2);
        const float mu = s * (1.f / 60.f);
        const float rs = rsqrtf(s2 * (1.f / 60.f) - mu * mu + 1e-5f);
#pragma unroll
        for (int j = 0; j < 8; ++j) {
            if (j < nd) {
                int d = c0 + 2 * j;
                float n0 = (xr[2 * j] - mu) * rs * g1[d] + b1[d];
                float n1 = (xr[2 * j + 1] - mu) * rs * g1[d + 1] + b1[d + 1];
                *(unsigned*)&R1[tk * 72 + d] = pk2(n0, n1);
            }
        }
        if (l4 == 3) {
#pragma unroll
            for (int u = 0; u < 3; ++u) *(unsigned*)&R1[tk * 72 + 60 + 2 * u] = 0;
        }
    }

    const int lane = tid & 63, r16 = lane & 15, g = lane >> 4;
    const int m0 = (tid >> 6) << 4;

    bf16x8 a0 = *(const bf16x8*)&R1[(m0 + r16) * 72 + g * 8];
    bf16x8 a1 = *(const bf16x8*)&R1[(m0 + r16) * 72 + 32 + g * 8];
    const float* btc = btab + (size_t)cls * 24576 + (m0 + r16) * 64;

    // ---- attention: two head-triples ----
    for (int p = 0; p < 2; ++p) {
        // B_p: qkv GEMM (N=96), bias via C-init, scatter q/k/v
#pragma unroll
        for (int nt = 0; nt < 6; ++nt) {
            const short* wr = pk + PK_QKV + (size_t)(p * 96 + nt * 16 + r16) * 72;
            bf16x8 w0 = *(const bf16x8*)(wr + g * 8);
            bf16x8 w1v = *(const bf16x8*)(wr + 32 + g * 8);
            int c = nt * 16 + r16;
            int which = 0, hl = 0, e = 0; float bias = 0.f;
            if (c < 90) {
                which = c / 30; int idx = c - which * 30;
                hl = idx / 10; e = idx - hl * 10;
                bias = qkv_b[which * 60 + (p * 3 + hl) * 10 + e];
                if (which == 0) bias *= QK_SCALE_L2E;
            }
            f32x4 acc = {bias, bias, bias, bias};
            acc = MFMA16(a0, w0, acc);
            acc = MFMA16(a1, w1v, acc);
            if (c < 90) {
                if (which == 0) {
#pragma unroll
                    for (int r = 0; r < 4; ++r)
                        R2[(m0 + g * 4 + r) * 104 + hl * 16 + e] = f2b(acc[r]);
                } else if (which == 1) {
#pragma unroll
                    for (int r = 0; r < 4; ++r)
                        R2[(m0 + g * 4 + r) * 104 + 48 + hl * 16 + e] = f2b(acc[r]);
                } else {
#pragma unroll
                    for (int r = 0; r < 2; ++r)
                        *(unsigned*)&R2[6656 + (hl * 10 + e) * 72 + m0 + g * 4 + 2 * r] =
                            pk2(acc[2 * r], acc[2 * r + 1]);
                }
            }
        }
        __syncthreads();

        // C_p: per head — swapped QK^T (log2e pre-folded), raw-exp2 softmax, PV.
        // Unrolled: 3 independent chains -> ILP.
#pragma unroll
        for (int hl = 0; hl < 3; ++hl) {
            const int h = p * 3 + hl;
            bf16x8 qa = Z8;
            if (g < 2) qa = *(const bf16x8*)&R2[(m0 + r16) * 104 + hl * 16 + g * 8];
            const float* bh = btc + h * 4096;
            f32x4 sv[4];
#pragma unroll
            for (int nt = 0; nt < 4; ++nt) {
                bf16x8 kb = Z8;
                if (g < 2) kb = *(const bf16x8*)&R2[(nt * 16 + r16) * 104 + 48 + hl * 16 + g * 8];
                sv[nt] = MFMA16(kb, qa, *(const f32x4*)&bh[nt * 16 + g * 4]);
            }
            // scores pre-scaled by log2e: bare v_exp_f32 (flushes masked -144 to 0)
            float sum = 0.f;
#pragma unroll
            for (int nt = 0; nt < 4; ++nt)
#pragma unroll
                for (int r = 0; r < 4; ++r) {
                    float e = EXP2RAW(sv[nt][r]);
                    sv[nt][r] = e; sum += e;
                }
            sum += __shfl_xor(sum, 16);
            sum += __shfl_xor(sum, 32);
            const float inv = 1.f / sum;

            unsigned qd00 = pk2(sv[0][0], sv[0][1]), qd01 = pk2(sv[0][2], sv[0][3]);
            unsigned qd10 = pk2(sv[1][0], sv[1][1]), qd11 = pk2(sv[1][2], sv[1][3]);
            unsigned qd20 = pk2(sv[2][0], sv[2][1]), qd21 = pk2(sv[2][2], sv[2][3]);
            unsigned qd30 = pk2(sv[3][0], sv[3][1]), qd31 = pk2(sv[3][2], sv[3][3]);
            const int sA = (r16 + ((g & 1) << 5)) << 2;
            const int sB = sA + 64;
            const bool hi = (g >> 1) & 1;
            union { unsigned u[4]; bf16x8 v; } pb0, pb1;
            {
                unsigned x0 = __builtin_amdgcn_ds_bpermute(sA, (int)qd00);
                unsigned y0 = __builtin_amdgcn_ds_bpermute(sA, (int)qd10);
                pb0.u[0] = hi ? y0 : x0;
                unsigned x1 = __builtin_amdgcn_ds_bpermute(sA, (int)qd01);
                unsigned y1 = __builtin_amdgcn_ds_bpermute(sA, (int)qd11);
                pb0.u[1] = hi ? y1 : x1;
                unsigned x2 = __builtin_amdgcn_ds_bpermute(sB, (int)qd00);
                unsigned y2 = __builtin_amdgcn_ds_bpermute(sB, (int)qd10);
                pb0.u[2] = hi ? y2 : x2;
                unsigned x3 = __builtin_amdgcn_ds_bpermute(sB, (int)qd01);
                unsigned y3 = __builtin_amdgcn_ds_bpermute(sB, (int)qd11);
                pb0.u[3] = hi ? y3 : x3;
                unsigned u0 = __builtin_amdgcn_ds_bpermute(sA, (int)qd20);
                unsigned v0 = __builtin_amdgcn_ds_bpermute(sA, (int)qd30);
                pb1.u[0] = hi ? v0 : u0;
                unsigned u1 = __builtin_amdgcn_ds_bpermute(sA, (int)qd21);
                unsigned v1 = __builtin_amdgcn_ds_bpermute(sA, (int)qd31);
                pb1.u[1] = hi ? v1 : u1;
                unsigned u2 = __builtin_amdgcn_ds_bpermute(sB, (int)qd20);
                unsigned v2 = __builtin_amdgcn_ds_bpermute(sB, (int)qd30);
                pb1.u[2] = hi ? v2 : u2;
                unsigned u3 = __builtin_amdgcn_ds_bpermute(sB, (int)qd21);
                unsigned v3 = __builtin_amdgcn_ds_bpermute(sB, (int)qd31);
                pb1.u[3] = hi ? v3 : u3;
            }
            // vT compact: rows hl*10 + r16, valid only r16<10 (guarded; Z8 else)
            bf16x8 va0 = Z8, va1 = Z8;
            if (r16 < 10) {
                va0 = *(const bf16x8*)&R2[6656 + (hl * 10 + r16) * 72 + g * 8];
                va1 = *(const bf16x8*)&R2[6656 + (hl * 10 + r16) * 72 + 32 + g * 8];
            }
            f32x4 o = MFMA16(va0, pb0.v, Z4);
            o = MFMA16(va1, pb1.v, o);
            if (g < 2) {
                *(unsigned*)&R1[(m0 + r16) * 72 + h * 10 + g * 4]     = pk2(o[0] * inv, o[1] * inv);
                *(unsigned*)&R1[(m0 + r16) * 72 + h * 10 + g * 4 + 2] = pk2(o[2] * inv, o[3] * inv);
            } else if (g == 2) {
                *(unsigned*)&R1[(m0 + r16) * 72 + h * 10 + 8] = pk2(o[0] * inv, o[1] * inv);
            }
        }
        __syncthreads();
    }

    // ---- D: proj (+bias) -> R1 rows (no residual here) ----
    {
        bf16x8 oa0 = *(const bf16x8*)&R1[(m0 + r16) * 72 + g * 8];
        bf16x8 oa1 = *(const bf16x8*)&R1[(m0 + r16) * 72 + 32 + g * 8];
#pragma unroll
        for (int nt = 0; nt < 4; ++nt) {
            const short* wr = pk + PK_PROJ + (size_t)(nt * 16 + r16) * 72;
            bf16x8 w0 = *(const bf16x8*)(wr + g * 8);
            bf16x8 w1v = *(const bf16x8*)(wr + 32 + g * 8);
            int d = nt * 16 + r16;
            float pb_ = (d < 60) ? proj_b[d] : 0.f;
            f32x4 acc = {pb_, pb_, pb_, pb_};
            acc = MFMA16(oa0, w0, acc);
            acc = MFMA16(oa1, w1v, acc);
            if (d < 60) {
#pragma unroll
                for (int r = 0; r < 4; ++r)
                    R1[(m0 + g * 4 + r) * 72 + d] = f2b(acc[r]);
            }
        }
    }

    // ---- E: residual (from xpk regs) + LN2; y -> R1, ln2 -> R2 ----
    if (L == 0) {
        float yv[15]; float s = 0.f, s2 = 0.f;
#pragma unroll
        for (int dd = 0; dd < 15; ++dd) {
            int d = l4 * 15 + dd;
            float xv = b2f((unsigned short)((dd & 1) ? (xpk[dd >> 1] >> 16)
                                                    : (xpk[dd >> 1] & 0xffff)));
            float y = xv + b2f((unsigned short)R1[tk * 72 + d]);
            yv[dd] = y; s += y; s2 += y * y;
        }
        s  += __shfl_xor(s, 1);  s  += __shfl_xor(s, 2);
        s2 += __shfl_xor(s2, 1); s2 += __shfl_xor(s2, 2);
        const float mu = s * (1.f / 60.f);
        const float rs = rsqrtf(s2 * (1.f / 60.f) - mu * mu + 1e-5f);
#pragma unroll
        for (int dd = 0; dd < 15; ++dd) {
            int d = l4 * 15 + dd;
            R1[tk * 72 + d] = f2b(yv[dd]);
            R2[tk * 136 + d] = f2b((yv[dd] - mu) * rs * g2[d] + b2[d]);
        }
#pragma unroll
        for (int u = 0; u < 3; ++u) R2[tk * 136 + 60 + l4 * 3 + u] = 0;
    } else {
        float yv[16]; float s = 0.f, s2 = 0.f;
        const int nd = (l4 == 3) ? 6 : 8, c0 = l4 * 16;
#pragma unroll
        for (int j = 0; j < 8; ++j) {
            if (j < nd) {
                int d = c0 + 2 * j;
                float y0 = b2f((unsigned short)(xpk[j] & 0xffff))
                         + b2f((unsigned short)R1[tk * 72 + d]);
                float y1 = b2f((unsigned short)(xpk[j] >> 16))
                         + b2f((unsigned short)R1[tk * 72 + d + 1]);
                yv[2 * j] = y0; yv[2 * j + 1] = y1;
                s += y0 + y1; s2 += y0 * y0 + y1 * y1;
            }
        }
        s  += __shfl_xor(s, 1);  s  += __shfl_xor(s, 2);
        s2 += __shfl_xor(s2, 1); s2 += __shfl_xor(s2, 2);
        const float mu = s * (1.f / 60.f);
        const float rs = rsqrtf(s2 * (1.f / 60.f) - mu * mu + 1e-5f);
#pragma unroll
        for (int j = 0; j < 8; ++j) {
            if (j < nd) {
                int d = c0 + 2 * j;
                *(unsigned*)&R1[tk * 72 + d] = pk2(yv[2 * j], yv[2 * j + 1]);
                float n0 = (yv[2 * j] - mu) * rs * g2[d] + b2[d];
                float n1 = (yv[2 * j + 1] - mu) * rs * g2[d + 1] + b2[d + 1];
                *(unsigned*)&R2[tk * 136 + d] = pk2(n0, n1);
            }
        }
        if (l4 == 3) {
#pragma unroll
            for (int u = 0; u < 3; ++u) *(unsigned*)&R2[tk * 136 + 60 + 2 * u] = 0;
        }
    }

    bf16x8 la0 = *(const bf16x8*)&R2[(m0 + r16) * 136 + g * 8];
    bf16x8 la1 = *(const bf16x8*)&R2[(m0 + r16) * 136 + 32 + g * 8];

    f32x4 acc2[4];
#pragma unroll
    for (int nt = 0; nt < 4; ++nt) {
        int d = nt * 16 + r16;
        float fb = (d < 60) ? fc2_b[d] : 0.f;
        acc2[nt] = (f32x4){fb, fb, fb, fb};
    }

    // F: GEMM1 half A (c 0..127) -> hb  (GELU via raw exp2, constants pre-folded)
#pragma unroll
    for (int nt = 0; nt < 8; ++nt) {
        const short* wr = pk + PK_W1 + (size_t)(nt * 16 + r16) * 72;
        bf16x8 w0 = *(const bf16x8*)(wr + g * 8);
        bf16x8 w1v = *(const bf16x8*)(wr + 32 + g * 8);
        int c = nt * 16 + r16;
        float fb = fc1_b[c];
        f32x4 acc = {fb, fb, fb, fb};
        acc = MFMA16(la0, w0, acc);
        acc = MFMA16(la1, w1v, acc);
#pragma unroll
        for (int r = 0; r < 4; ++r) {
            float u = acc[r];
            float zz = 2.302208235f * u + 0.10294353f * (u * u * u);
            float ge = u * __builtin_amdgcn_rcpf(1.f + EXP2RAW(-zz));
            R2[(m0 + g * 4 + r) * 136 + c] = f2b(ge);
        }
    }
    // G: GEMM2 pass 1 (K 0..127)
#pragma unroll
    for (int kk = 0; kk < 4; ++kk) {
        bf16x8 ha = *(const bf16x8*)&R2[(m0 + r16) * 136 + kk * 32 + g * 8];
#pragma unroll
        for (int nt = 0; nt < 4; ++nt) {
            const short* wr = pk + PK_W2 + (size_t)(nt * 16 + r16) * 264 + kk * 32 + g * 8;
            acc2[nt] = MFMA16(ha, *(const bf16x8*)wr, acc2[nt]);
        }
    }
    // zero hb cols 112..127 (own rows)
    *(int*)&R2[(m0 + r16) * 136 + 112 + g * 4]     = 0;
    *(int*)&R2[(m0 + r16) * 136 + 112 + g * 4 + 2] = 0;
    // H: GEMM1 half B (c 128..239) -> hb cols 0..111
#pragma unroll
    for (int nt = 0; nt < 7; ++nt) {
        const short* wr = pk + PK_W1 + (size_t)(128 + nt * 16 + r16) * 72;
        bf16x8 w0 = *(const bf16x8*)(wr + g * 8);
        bf16x8 w1v = *(const bf16x8*)(wr + 32 + g * 8);
        int c = nt * 16 + r16;
        float fb = fc1_b[128 + c];
        f32x4 acc = {fb, fb, fb, fb};
        acc = MFMA16(la0, w0, acc);
        acc = MFMA16(la1, w1v, acc);
#pragma unroll
        for (int r = 0; r < 4; ++r) {
            float u = acc[r];
            float zz = 2.302208235f * u + 0.10294353f * (u * u * u);
            float ge = u * __builtin_amdgcn_rcpf(1.f + EXP2RAW(-zz));
            R2[(m0 + g * 4 + r) * 136 + c] = f2b(ge);
        }
    }
    // I: GEMM2 pass 2 (K 128..255)
#pragma unroll
    for (int kk = 0; kk < 4; ++kk) {
        bf16x8 ha = *(const bf16x8*)&R2[(m0 + r16) * 136 + kk * 32 + g * 8];
#pragma unroll
        for (int nt = 0; nt < 4; ++nt) {
            const short* wr = pk + PK_W2 + (size_t)(nt * 16 + r16) * 264 + 128 + kk * 32 + g * 8;
            acc2[nt] = MFMA16(ha, *(const bf16x8*)wr, acc2[nt]);
        }
    }

    // ---- epilogue: v = y + mlp; stage, then coalesced store ----
#pragma unroll
    for (int nt = 0; nt < 4; ++nt) {
        int d = nt * 16 + r16;
        if (d < 60) {
#pragma unroll
            for (int r = 0; r < 4; ++r) {
                float yv = b2f((unsigned short)R1[(m0 + g * 4 + r) * 72 + d]);
                float v = yv + acc2[nt][r];
                if (L == 0) R2[(m0 + g * 4 + r) * 136 + d] = f2b(v);
                else        ((float*)R2)[(m0 + g * 4 + r) * 68 + d] = v;
            }
        }
    }
    __syncthreads();

    if (L == 0) {
        unsigned* ob = (unsigned*)xout_v;
        const size_t gbase = (size_t)b * NTOK * 30;
        for (int i = tid; i < 1920; i += 256) {
            int r = i / 30, c = i - r * 30;
            int gt = ((wy * 8 + (r >> 3)) << 6) + wx * 8 + (r & 7);
            ob[gbase + (size_t)gt * 30 + c] = *(unsigned*)&R2[r * 136 + 2 * c];
        }
    } else {
        float* of = (float*)xout_v;
        for (int i = tid; i < 3840; i += 256) {
            int d = i >> 6, t = i & 63;
            int gt = (((wy * 8 + (t >> 3) + 4) & 63) << 6) + ((wx * 8 + (t & 7) + 4) & 63);
            of[(size_t)d * NTOT + b * NTOK + gt] = ((const float*)R2)[t * 68 + d];
        }
    }
}

extern "C" void kernel_launch(void* const* d_in, const int* in_sizes, int n_in,
                              void* d_out, int out_size, void* d_ws, size_t ws_size,
                              hipStream_t stream)
{
    const float* x       = (const float*)d_in[0];
    const float* norm1_g = (const float*)d_in[1];
    const float* norm1_b = (const float*)d_in[2];
    const float* qkv_w   = (const float*)d_in[3];
    const float* qkv_b   = (const float*)d_in[4];
    const float* rpb     = (const float*)d_in[5];
    const float* proj_w  = (const float*)d_in[6];
    const float* proj_b  = (const float*)d_in[7];
    const float* norm2_g = (const float*)d_in[8];
    const float* norm2_b = (const float*)d_in[9];
    const float* fc1_w   = (const float*)d_in[10];
    const float* fc1_b   = (const float*)d_in[11];
    const float* fc2_w   = (const float*)d_in[12];
    const float* fc2_b   = (const float*)d_in[13];

    unsigned short* bufA = (unsigned short*)d_ws;
    short* pk  = (short*)((char*)d_ws + (size_t)NTOT * DIM * 2);
    float* btab = (float*)((char*)pk + 2 * PK_STRIDE * 2);

    dim3 block(256);
    pack_w<<<dim3(2, 64), block, 0, stream>>>(qkv_w, proj_w, fc1_w, fc2_w, rpb, pk, btab);

    dim3 grid(NB * 64);
    swin_layer<0><<<grid, block, 0, stream>>>(
        (const void*)x, (void*)bufA,
        norm1_g, norm1_b, norm2_g, norm2_b, pk, btab,
        qkv_b, proj_b, fc1_b, fc2_b);
    swin_layer<1><<<grid, block, 0, stream>>>(
        (const void*)bufA, d_out,
        norm1_g + 60, norm1_b + 60, norm2_g + 60, norm2_b + 60,
        pk + PK_STRIDE, btab + 4 * 24576,
        qkv_b + 180, proj_b + 60, fc1_b + 240, fc2_b + 60);

    (void)in_sizes; (void)n_in; (void)out_size; (void)ws_size;
}